// Round 12
// baseline (30.707 us; speedup 1.0000x reference)
//
#include <hip/hip_runtime.h>
#include <hip/hip_bf16.h>
#include <math.h>

// B=2, L=5, C=32, H=48, W=176, NUM_ITER=1.
// Cuts: only i=0 slice matters (R1); conv = warped-half (per j) + ego-half (per b) (R1);
// conv as tap-wise implicit GEMM on MFMA bf16 (R3); 2-kernel split frozen (R4/R9/R10).
// R10: LDS-staged weights + rolling A-prefetch in k_fused; paired-tap float2 gathers.
// R11: XCD-residue work mapping in k_prep. R12: weight pack moved from k_prep into
// k_fused's LDS staging (reads fp32 originals, converts in-stage) — k_prep shrinks to
// 1584 blocks (8 x (132 local-image + 66 leftover)), Wp/Wp2 buffers deleted.
#define BB 2
#define LL 5
#define CC 32
#define HH 48
#define WW 176
#define HWs (HH * WW)          // 8448
#define BL (BB * LL)           // 10
#define WROW 36                // padded LDS weight row stride (ushorts; 72B, 8B-aligned)

typedef __attribute__((ext_vector_type(8))) short bf16x8;
typedef __attribute__((ext_vector_type(4))) float f32x4;

__device__ __forceinline__ unsigned short f2bf(float v) {
    __hip_bfloat16 h = __float2bfloat16(v);   // RNE
    return *reinterpret_cast<unsigned short*>(&h);
}
__device__ __forceinline__ float bf2f(unsigned short u) {
    __hip_bfloat16 h = *reinterpret_cast<__hip_bfloat16*>(&u);
    return __bfloat162float(h);
}

// ---- K_prep (flat 1D grid, 1584 blocks): XCD-residue work mapping.
//   id%8 == r, q = id>>3 (0..197):
//     q < 132 -> warp image y = r (XCD-local source image)
//     q >= 132 -> lid = r*66 + (q-132) in 0..527: y = 8 + lid/132 (8,9 warp; 10,11 ego)
__global__ __launch_bounds__(256) void k_prep(const float* __restrict__ x,
                                              const float* __restrict__ M,
                                              unsigned short* __restrict__ warpedcl,
                                              unsigned short* __restrict__ egocl,
                                              float* __restrict__ maskb)
{
    int id = blockIdx.x;
    int r  = id & 7, q = id >> 3;
    int y, unit;
    if (q < 132) {
        y = r; unit = q;
    } else {
        int lid = r * 66 + (q - 132);      // 0..527
        y = 8 + lid / 132;                 // 8..11
        unit = lid % 132;
    }
    int xb = unit % 33;                    // 33 x-blocks of 256 pixels
    int cg = unit / 33;                    // 0..3 channel groups

    if (y < BL) {
        int pix = xb * 256 + threadIdx.x;
        int w = pix % WW, h = pix / WW;
        int b = y / LL, j = y % LL;
        const float* Mp = M + (size_t)(b * LL * LL + j) * 6;   // M[b][0][j]

        float xs = (2.0f * (float)w + 1.0f) / (float)WW - 1.0f;
        float ys = (2.0f * (float)h + 1.0f) / (float)HH - 1.0f;
        float gx = Mp[0] * xs + Mp[1] * ys + Mp[2];
        float gy = Mp[3] * xs + Mp[4] * ys + Mp[5];
        float ix = ((gx + 1.0f) * (float)WW - 1.0f) * 0.5f;
        float iy = ((gy + 1.0f) * (float)HH - 1.0f) * 0.5f;
        float x0f = floorf(ix), y0f = floorf(iy);
        float wx = ix - x0f, wy = iy - y0f;
        float x1f = x0f + 1.0f, y1f = y0f + 1.0f;
        bool vx0 = (x0f >= 0.0f) && (x0f <= (float)(WW - 1));
        bool vx1 = (x1f >= 0.0f) && (x1f <= (float)(WW - 1));
        bool vy0 = (y0f >= 0.0f) && (y0f <= (float)(HH - 1));
        bool vy1 = (y1f >= 0.0f) && (y1f <= (float)(HH - 1));
        int xi0 = (int)fminf(fmaxf(x0f, 0.0f), (float)(WW - 1));
        int yi0 = (int)fminf(fmaxf(y0f, 0.0f), (float)(HH - 1));
        int yi1 = (int)fminf(fmaxf(y1f, 0.0f), (float)(HH - 1));
        float a00 = (vx0 && vy0) ? (1.0f - wx) * (1.0f - wy) : 0.0f;
        float a10 = (vx1 && vy0) ? wx * (1.0f - wy) : 0.0f;
        float a01 = (vx0 && vy1) ? (1.0f - wx) * wy : 0.0f;
        float a11 = (vx1 && vy1) ? wx * wy : 0.0f;

        if (cg == 0)
            maskb[(size_t)y * HWs + pix] = a00 + a10 + a01 + a11;

        // x-adjacency: xi1 == xi0+1 iff x0f>=0 && x1f<=W-2; otherwise xi1==xi0 and the
        // invalid side's weight is 0, so one scalar serves both taps (bit-exact).
        bool adjx = (x0f >= 0.0f) && (x0f <= (float)(WW - 2));
        int oL0 = yi0 * WW + xi0;
        int oL1 = yi1 * WW + xi0;

        const float* img = x + (size_t)y * CC * HWs + (size_t)cg * 8 * HWs;
        bf16x8 v8;
#pragma unroll
        for (int c = 0; c < 8; ++c) {
            const float* qp = img + (size_t)c * HWs;
            float v00, v10, v01, v11;
            if (adjx) {
                float2 u0 = *(const float2*)(qp + oL0);
                float2 u1 = *(const float2*)(qp + oL1);
                v00 = u0.x; v10 = u0.y; v01 = u1.x; v11 = u1.y;
            } else {
                v00 = v10 = qp[oL0];
                v01 = v11 = qp[oL1];
            }
            float v = a00 * v00 + a10 * v10 + a01 * v01 + a11 * v11;
            v8[c] = (short)f2bf(v);
        }
        *(bf16x8*)(warpedcl + ((size_t)y * HWs + pix) * CC + cg * 8) = v8;
    } else {
        int b = y - BL;
        int pix = xb * 256 + threadIdx.x;
        const float* img = x + (size_t)(b * LL) * CC * HWs + (size_t)cg * 8 * HWs;
        bf16x8 v8;
#pragma unroll
        for (int c = 0; c < 8; ++c)
            v8[c] = (short)f2bf(img[(size_t)c * HWs + pix]);
        *(bf16x8*)(egocl + ((size_t)b * HWs + pix) * CC + cg * 8) = v8;
    }
}

// read one B-fragment (8 bf16 elems) from padded LDS weight array
__device__ __forceinline__ bf16x8 ldfrag(const unsigned short* __restrict__ wl,
                                         int row, int kblk)
{
    const unsigned short* p = wl + row * WROW + kblk * 8;   // 8B-aligned
    ushort4 u0 = *(const ushort4*)(p);
    ushort4 u1 = *(const ushort4*)(p + 4);
    bf16x8 r;
    r[0] = (short)u0.x; r[1] = (short)u0.y; r[2] = (short)u0.z; r[3] = (short)u0.w;
    r[4] = (short)u1.x; r[5] = (short)u1.y; r[6] = (short)u1.z; r[7] = (short)u1.w;
    return r;
}

// ---- K_fused: per-wave 16-pixel tile; weights fp32->bf16 staged to LDS in-kernel;
//      rolling A-prefetch; 6 half-convs + bias + mask*max + skip + mlp MFMA ----
__global__ __launch_bounds__(256) void k_fused(const unsigned short* __restrict__ warpedcl,
                                               const unsigned short* __restrict__ egocl,
                                               const float* __restrict__ maskb,
                                               const float* __restrict__ msg_w,
                                               const float* __restrict__ mlp_w,
                                               const float* __restrict__ msg_b,
                                               const float* __restrict__ mlp_b,
                                               float* __restrict__ out)
{
    __shared__ unsigned short wlds[608 * WROW];   // rows 0..575 msg [ht][oc][ic], 576..607 mlp
    __shared__ float fl[64][33];

    const int tid  = threadIdx.x;
    const int wv   = tid >> 6;
    const int lane = tid & 63;
    const int lo   = lane & 15;
    const int kblk = lane >> 4;
    const int b    = blockIdx.y;
    const int p0   = blockIdx.x * 64 + wv * 16;
    const int pf   = p0 + lo;
    const int ph   = pf / WW, pw = pf % WW;

    // ---- stage msg_w (18432 fp32) -> wlds bf16, layout row=(half*9+tap)*32+oc, col=ic ----
    // coalesced float4 reads; scatter ds_write_b16 (cheap); math bit-identical to old pack.
#pragma unroll
    for (int k = 0; k < 18; ++k) {
        int idx4 = k * 256 + tid;
        float4 vv = *(const float4*)(msg_w + 4 * idx4);
        float ve[4] = {vv.x, vv.y, vv.z, vv.w};
#pragma unroll
        for (int e = 0; e < 4; ++e) {
            int i = 4 * idx4 + e;
            int oc = i / 576, rem = i % 576;
            int icg = rem / 9, tap = rem % 9;
            int half = icg >> 5, ic = icg & 31;
            wlds[((half * 9 + tap) * 32 + oc) * WROW + ic] = f2bf(ve[e]);
        }
    }
    // ---- stage mlp_w (1024 fp32) -> rows 576..607 ----
    {
        float4 vv = *(const float4*)(mlp_w + 4 * tid);
        float ve[4] = {vv.x, vv.y, vv.z, vv.w};
#pragma unroll
        for (int e = 0; e < 4; ++e) {
            int i = 4 * tid + e;
            wlds[(576 + (i >> 5)) * WROW + (i & 31)] = f2bf(ve[e]);
        }
    }

    // per-tap safe source pixel + validity (overlaps with staging)
    int ps[9];
    unsigned vbits = 0;
#pragma unroll
    for (int tap = 0; tap < 9; ++tap) {
        int dy = tap / 3 - 1, dx = tap % 3 - 1;
        int hh = ph + dy, wwp = pw + dx;
        bool valid = (hh >= 0) && (hh < HH) && (wwp >= 0) && (wwp < WW);
        ps[tap] = valid ? (pf + dy * WW + dx) : pf;
        vbits |= (valid ? 1u : 0u) << tap;
    }
    const bf16x8 zero = {0, 0, 0, 0, 0, 0, 0, 0};

    // issue ego A-frags + all masks early (fly under the barrier)
    bf16x8 afe[9];
    const unsigned short* Ae = egocl + (size_t)b * HWs * CC;
#pragma unroll
    for (int tap = 0; tap < 9; ++tap)
        afe[tap] = *(const bf16x8*)(Ae + (size_t)ps[tap] * CC + kblk * 8);
    float4 mks[LL];
#pragma unroll
    for (int j = 0; j < LL; ++j)
        mks[j] = *(const float4*)(maskb + (size_t)(b * LL + j) * HWs + p0 + kblk * 4);

    __syncthreads();

    // B-frags for warped half from LDS (kept in regs across all 5 j)
    bf16x8 Bw[9][2];
#pragma unroll
    for (int tap = 0; tap < 9; ++tap)
#pragma unroll
        for (int nt = 0; nt < 2; ++nt)
            Bw[tap][nt] = ldfrag(wlds, tap * 32 + nt * 16 + lo, kblk);

    // ego half-conv (+ conv bias); ego B-frags read from LDS on the fly
    f32x4 acce[2] = {};
#pragma unroll
    for (int tap = 0; tap < 9; ++tap) {
        bf16x8 a = ((vbits >> tap) & 1) ? afe[tap] : zero;
#pragma unroll
        for (int nt = 0; nt < 2; ++nt) {
            bf16x8 Be = ldfrag(wlds, 288 + tap * 32 + nt * 16 + lo, kblk);
            acce[nt] = __builtin_amdgcn_mfma_f32_16x16x32_bf16(a, Be, acce[nt], 0, 0, 0);
        }
    }
    {
        float b0 = msg_b[lo], b1 = msg_b[16 + lo];
#pragma unroll
        for (int r = 0; r < 4; ++r) { acce[0][r] += b0; acce[1][r] += b1; }
    }

    // rolling 3-buffer A-prefetch over j (full unroll -> static indices)
    bf16x8 afw[3][9];
#pragma unroll
    for (int jj = 0; jj < 2; ++jj) {
        const unsigned short* Aw = warpedcl + (size_t)(b * LL + jj) * HWs * CC;
#pragma unroll
        for (int tap = 0; tap < 9; ++tap)
            afw[jj][tap] = *(const bf16x8*)(Aw + (size_t)ps[tap] * CC + kblk * 8);
    }

    f32x4 agg[2];
#pragma unroll
    for (int r = 0; r < 4; ++r) { agg[0][r] = -INFINITY; agg[1][r] = -INFINITY; }

#pragma unroll
    for (int j = 0; j < LL; ++j) {
        if (j + 2 < LL) {
            const unsigned short* Aw = warpedcl + (size_t)(b * LL + j + 2) * HWs * CC;
#pragma unroll
            for (int tap = 0; tap < 9; ++tap)
                afw[(j + 2) % 3][tap] = *(const bf16x8*)(Aw + (size_t)ps[tap] * CC + kblk * 8);
        }
        f32x4 acc[2] = {};
#pragma unroll
        for (int tap = 0; tap < 9; ++tap) {
            bf16x8 a = ((vbits >> tap) & 1) ? afw[j % 3][tap] : zero;
#pragma unroll
            for (int nt = 0; nt < 2; ++nt)
                acc[nt] = __builtin_amdgcn_mfma_f32_16x16x32_bf16(a, Bw[tap][nt], acc[nt], 0, 0, 0);
        }
        float mkr[4] = {mks[j].x, mks[j].y, mks[j].z, mks[j].w};
#pragma unroll
        for (int nt = 0; nt < 2; ++nt)
#pragma unroll
            for (int r = 0; r < 4; ++r)
                agg[nt][r] = fmaxf(agg[nt][r], (acc[nt][r] + acce[nt][r]) * mkr[r]);
    }

    // f = agg + skip(egocl bf16) -> per-wave LDS transpose -> mlp MFMA
#pragma unroll
    for (int nt = 0; nt < 2; ++nt)
#pragma unroll
        for (int r = 0; r < 4; ++r) {
            int pixl = kblk * 4 + r;
            float skip = bf2f(egocl[((size_t)b * HWs + p0 + pixl) * CC + nt * 16 + lo]);
            fl[wv * 16 + pixl][nt * 16 + lo] = agg[nt][r] + skip;
        }
    // same-wave LDS read-back (lgkmcnt ordering; no cross-wave sharing)
    bf16x8 Afm;
#pragma unroll
    for (int e = 0; e < 8; ++e)
        Afm[e] = (short)f2bf(fl[wv * 16 + lo][kblk * 8 + e]);

#pragma unroll
    for (int nt2 = 0; nt2 < 2; ++nt2) {
        bf16x8 Bm = ldfrag(wlds, 576 + nt2 * 16 + lo, kblk);
        f32x4 om = {};
        om = __builtin_amdgcn_mfma_f32_16x16x32_bf16(Afm, Bm, om, 0, 0, 0);
        float mb2 = mlp_b[nt2 * 16 + lo];
        int d = nt2 * 16 + lo;
#pragma unroll
        for (int r = 0; r < 4; ++r)
            out[((size_t)b * CC + d) * HWs + p0 + kblk * 4 + r] = om[r] + mb2;
    }
}

extern "C" void kernel_launch(void* const* d_in, const int* in_sizes, int n_in,
                              void* d_out, int out_size, void* d_ws, size_t ws_size,
                              hipStream_t stream)
{
    (void)in_sizes; (void)n_in; (void)out_size; (void)ws_size;
    const float* x     = (const float*)d_in[0];
    // d_in[1] = record_len (unused by reference)
    const float* M     = (const float*)d_in[2];
    const float* msg_w = (const float*)d_in[3];
    const float* msg_b = (const float*)d_in[4];
    const float* mlp_w = (const float*)d_in[5];
    const float* mlp_b = (const float*)d_in[6];
    float* out = (float*)d_out;

    // workspace layout (all segments 16B-aligned)
    unsigned short* warpedcl = (unsigned short*)d_ws;                    // BL*HW*C bf16
    unsigned short* egocl    = warpedcl + (size_t)BL * HWs * CC;         // BB*HW*C bf16
    float*          maskb    = (float*)(egocl + (size_t)BB * HWs * CC);  // BL*HW f32

    {
        k_prep<<<dim3(1584), 256, 0, stream>>>(x, M, warpedcl, egocl, maskb);
    }
    {
        dim3 g(HWs / 64, BB);                // (132, 2)
        k_fused<<<g, 256, 0, stream>>>(warpedcl, egocl, maskb, msg_w, mlp_w,
                                       msg_b, mlp_b, out);
    }
}

// Round 13
// 26.970 us; speedup vs baseline: 1.1385x; 1.1385x over previous
//
#include <hip/hip_runtime.h>
#include <hip/hip_bf16.h>
#include <math.h>

// B=2, L=5, C=32, H=48, W=176, NUM_ITER=1.
// Cuts: only i=0 slice matters (R1); conv = warped-half (per j) + ego-half (per b) (R1);
// conv as tap-wise implicit GEMM on MFMA bf16 (R3); 2-kernel split frozen (R4/R9/R10).
// R10: LDS-staged weights + rolling A-prefetch in k_fused; paired-tap float2 gathers.
// R11: XCD-residue work mapping in k_prep. (R12's in-kernel weight pack regressed —
// per-block fp32 re-read herd — reverted. R13 == R11, best-measured 26.98 us.)
#define BB 2
#define LL 5
#define CC 32
#define HH 48
#define WW 176
#define HWs (HH * WW)          // 8448
#define BL (BB * LL)           // 10
#define WROW 36                // padded LDS weight row stride (ushorts; 72B, 8B-aligned)

typedef __attribute__((ext_vector_type(8))) short bf16x8;
typedef __attribute__((ext_vector_type(4))) float f32x4;

__device__ __forceinline__ unsigned short f2bf(float v) {
    __hip_bfloat16 h = __float2bfloat16(v);   // RNE
    return *reinterpret_cast<unsigned short*>(&h);
}
__device__ __forceinline__ float bf2f(unsigned short u) {
    __hip_bfloat16 h = *reinterpret_cast<__hip_bfloat16*>(&u);
    return __bfloat162float(h);
}

// ---- K_prep (flat 1D grid, 1716 blocks): XCD-residue work mapping.
//   id%8 == r, q = id>>3:
//     q < 132          -> warp image y = r            (XCD-local source image)
//     q >= 132         -> leftover lid = leftoff(r)+(q-132): images 8,9; ego 10,11; pack 12
__global__ __launch_bounds__(256) void k_prep(const float* __restrict__ x,
                                              const float* __restrict__ M,
                                              const float* __restrict__ msg_w,
                                              const float* __restrict__ mlp_w,
                                              unsigned short* __restrict__ warpedcl,
                                              unsigned short* __restrict__ egocl,
                                              float* __restrict__ maskb,
                                              unsigned short* __restrict__ Wp,
                                              unsigned short* __restrict__ Wp2)
{
    int id = blockIdx.x;
    int r  = id & 7, q = id >> 3;
    int y, unit;
    if (q < 132) {
        y = r; unit = q;
    } else {
        // leftover pool: r<4 contributes 83 blocks (q=132..214), r>=4 contributes 82
        int leftoff = (r < 4) ? r * 83 : 332 + (r - 4) * 82;
        int lid = leftoff + (q - 132);     // 0..659
        y = 8 + lid / 132;                 // 8..12
        unit = lid % 132;
    }
    int xb = unit % 33;                    // 33 x-blocks of 256 pixels
    int cg = unit / 33;                    // 0..3 channel groups

    if (y < BL) {
        int pix = xb * 256 + threadIdx.x;
        int w = pix % WW, h = pix / WW;
        int b = y / LL, j = y % LL;
        const float* Mp = M + (size_t)(b * LL * LL + j) * 6;   // M[b][0][j]

        float xs = (2.0f * (float)w + 1.0f) / (float)WW - 1.0f;
        float ys = (2.0f * (float)h + 1.0f) / (float)HH - 1.0f;
        float gx = Mp[0] * xs + Mp[1] * ys + Mp[2];
        float gy = Mp[3] * xs + Mp[4] * ys + Mp[5];
        float ix = ((gx + 1.0f) * (float)WW - 1.0f) * 0.5f;
        float iy = ((gy + 1.0f) * (float)HH - 1.0f) * 0.5f;
        float x0f = floorf(ix), y0f = floorf(iy);
        float wx = ix - x0f, wy = iy - y0f;
        float x1f = x0f + 1.0f, y1f = y0f + 1.0f;
        bool vx0 = (x0f >= 0.0f) && (x0f <= (float)(WW - 1));
        bool vx1 = (x1f >= 0.0f) && (x1f <= (float)(WW - 1));
        bool vy0 = (y0f >= 0.0f) && (y0f <= (float)(HH - 1));
        bool vy1 = (y1f >= 0.0f) && (y1f <= (float)(HH - 1));
        int xi0 = (int)fminf(fmaxf(x0f, 0.0f), (float)(WW - 1));
        int yi0 = (int)fminf(fmaxf(y0f, 0.0f), (float)(HH - 1));
        int yi1 = (int)fminf(fmaxf(y1f, 0.0f), (float)(HH - 1));
        float a00 = (vx0 && vy0) ? (1.0f - wx) * (1.0f - wy) : 0.0f;
        float a10 = (vx1 && vy0) ? wx * (1.0f - wy) : 0.0f;
        float a01 = (vx0 && vy1) ? (1.0f - wx) * wy : 0.0f;
        float a11 = (vx1 && vy1) ? wx * wy : 0.0f;

        if (cg == 0)
            maskb[(size_t)y * HWs + pix] = a00 + a10 + a01 + a11;

        // x-adjacency: xi1 == xi0+1 iff x0f>=0 && x1f<=W-2; otherwise xi1==xi0 and the
        // invalid side's weight is 0, so one scalar serves both taps (bit-exact).
        bool adjx = (x0f >= 0.0f) && (x0f <= (float)(WW - 2));
        int oL0 = yi0 * WW + xi0;
        int oL1 = yi1 * WW + xi0;

        const float* img = x + (size_t)y * CC * HWs + (size_t)cg * 8 * HWs;
        bf16x8 v8;
#pragma unroll
        for (int c = 0; c < 8; ++c) {
            const float* qp = img + (size_t)c * HWs;
            float v00, v10, v01, v11;
            if (adjx) {
                float2 u0 = *(const float2*)(qp + oL0);
                float2 u1 = *(const float2*)(qp + oL1);
                v00 = u0.x; v10 = u0.y; v01 = u1.x; v11 = u1.y;
            } else {
                v00 = v10 = qp[oL0];
                v01 = v11 = qp[oL1];
            }
            float v = a00 * v00 + a10 * v10 + a01 * v01 + a11 * v11;
            v8[c] = (short)f2bf(v);
        }
        *(bf16x8*)(warpedcl + ((size_t)y * HWs + pix) * CC + cg * 8) = v8;
    } else if (y < BL + BB) {
        int b = y - BL;
        int pix = xb * 256 + threadIdx.x;
        const float* img = x + (size_t)(b * LL) * CC * HWs + (size_t)cg * 8 * HWs;
        bf16x8 v8;
#pragma unroll
        for (int c = 0; c < 8; ++c)
            v8[c] = (short)f2bf(img[(size_t)c * HWs + pix]);
        *(bf16x8*)(egocl + ((size_t)b * HWs + pix) * CC + cg * 8) = v8;
    } else {
        int i = (cg * 33 + xb) * 256 + threadIdx.x;
        if (i < 2 * 9 * 32 * 32) {
            int half = i / (9 * 32 * 32);
            int rr   = i % (9 * 32 * 32);
            int tap  = rr / (32 * 32);
            int r2   = rr % (32 * 32);
            int oc   = r2 / 32;
            int ic   = r2 % 32;
            Wp[i] = f2bf(msg_w[(size_t)oc * 576 + (size_t)(half * 32 + ic) * 9 + tap]);
        } else if (i < 2 * 9 * 32 * 32 + 32 * 32) {
            int k = i - 2 * 9 * 32 * 32;
            Wp2[k] = f2bf(mlp_w[k]);     // [d][c] row-major, as stored
        }
    }
}

// read one B-fragment (8 bf16 elems) from padded LDS weight array
__device__ __forceinline__ bf16x8 ldfrag(const unsigned short* __restrict__ wl,
                                         int row, int kblk)
{
    const unsigned short* p = wl + row * WROW + kblk * 8;   // 8B-aligned
    ushort4 u0 = *(const ushort4*)(p);
    ushort4 u1 = *(const ushort4*)(p + 4);
    bf16x8 r;
    r[0] = (short)u0.x; r[1] = (short)u0.y; r[2] = (short)u0.z; r[3] = (short)u0.w;
    r[4] = (short)u1.x; r[5] = (short)u1.y; r[6] = (short)u1.z; r[7] = (short)u1.w;
    return r;
}

// ---- K_fused: per-wave 16-pixel tile; weights LDS-staged once/block; rolling
//      A-prefetch; 6 half-convs + bias + mask*max + skip + mlp MFMA ----
__global__ __launch_bounds__(256) void k_fused(const unsigned short* __restrict__ warpedcl,
                                               const unsigned short* __restrict__ egocl,
                                               const float* __restrict__ maskb,
                                               const unsigned short* __restrict__ Wp,
                                               const unsigned short* __restrict__ Wp2,
                                               const float* __restrict__ msg_b,
                                               const float* __restrict__ mlp_b,
                                               float* __restrict__ out)
{
    __shared__ unsigned short wlds[608 * WROW];   // 43,776 B: rows 0..575 msg, 576..607 mlp
    __shared__ float fl[64][33];                  //  8,448 B

    const int tid  = threadIdx.x;
    const int wv   = tid >> 6;
    const int lane = tid & 63;
    const int lo   = lane & 15;
    const int kblk = lane >> 4;
    const int b    = blockIdx.y;
    const int p0   = blockIdx.x * 64 + wv * 16;
    const int pf   = p0 + lo;
    const int ph   = pf / WW, pw = pf % WW;

    // ---- stage Wp (18432) + Wp2 (1024, contiguous after Wp) into padded LDS ----
#pragma unroll
    for (int k = 0; k < 19; ++k) {
        int g = k * 256 + tid;
        ushort4 u = *(const ushort4*)(Wp + 4 * g);       // coalesced 8B global
        int row = g >> 3, col = (g & 7) * 4;
        *(ushort4*)(wlds + row * WROW + col) = u;        // 8B-aligned ds_write
    }

    // per-tap safe source pixel + validity (overlaps with staging)
    int ps[9];
    unsigned vbits = 0;
#pragma unroll
    for (int tap = 0; tap < 9; ++tap) {
        int dy = tap / 3 - 1, dx = tap % 3 - 1;
        int hh = ph + dy, wwp = pw + dx;
        bool valid = (hh >= 0) && (hh < HH) && (wwp >= 0) && (wwp < WW);
        ps[tap] = valid ? (pf + dy * WW + dx) : pf;
        vbits |= (valid ? 1u : 0u) << tap;
    }
    const bf16x8 zero = {0, 0, 0, 0, 0, 0, 0, 0};

    // issue ego A-frags + all masks early (fly under the barrier)
    bf16x8 afe[9];
    const unsigned short* Ae = egocl + (size_t)b * HWs * CC;
#pragma unroll
    for (int tap = 0; tap < 9; ++tap)
        afe[tap] = *(const bf16x8*)(Ae + (size_t)ps[tap] * CC + kblk * 8);
    float4 mks[LL];
#pragma unroll
    for (int j = 0; j < LL; ++j)
        mks[j] = *(const float4*)(maskb + (size_t)(b * LL + j) * HWs + p0 + kblk * 4);

    __syncthreads();

    // B-frags for warped half from LDS (kept in regs across all 5 j)
    bf16x8 Bw[9][2];
#pragma unroll
    for (int tap = 0; tap < 9; ++tap)
#pragma unroll
        for (int nt = 0; nt < 2; ++nt)
            Bw[tap][nt] = ldfrag(wlds, tap * 32 + nt * 16 + lo, kblk);

    // ego half-conv (+ conv bias); ego B-frags read from LDS on the fly
    f32x4 acce[2] = {};
#pragma unroll
    for (int tap = 0; tap < 9; ++tap) {
        bf16x8 a = ((vbits >> tap) & 1) ? afe[tap] : zero;
#pragma unroll
        for (int nt = 0; nt < 2; ++nt) {
            bf16x8 Be = ldfrag(wlds, 288 + tap * 32 + nt * 16 + lo, kblk);
            acce[nt] = __builtin_amdgcn_mfma_f32_16x16x32_bf16(a, Be, acce[nt], 0, 0, 0);
        }
    }
    {
        float b0 = msg_b[lo], b1 = msg_b[16 + lo];
#pragma unroll
        for (int r = 0; r < 4; ++r) { acce[0][r] += b0; acce[1][r] += b1; }
    }

    // rolling 3-buffer A-prefetch over j (full unroll -> static indices)
    bf16x8 afw[3][9];
#pragma unroll
    for (int jj = 0; jj < 2; ++jj) {
        const unsigned short* Aw = warpedcl + (size_t)(b * LL + jj) * HWs * CC;
#pragma unroll
        for (int tap = 0; tap < 9; ++tap)
            afw[jj][tap] = *(const bf16x8*)(Aw + (size_t)ps[tap] * CC + kblk * 8);
    }

    f32x4 agg[2];
#pragma unroll
    for (int r = 0; r < 4; ++r) { agg[0][r] = -INFINITY; agg[1][r] = -INFINITY; }

#pragma unroll
    for (int j = 0; j < LL; ++j) {
        if (j + 2 < LL) {
            const unsigned short* Aw = warpedcl + (size_t)(b * LL + j + 2) * HWs * CC;
#pragma unroll
            for (int tap = 0; tap < 9; ++tap)
                afw[(j + 2) % 3][tap] = *(const bf16x8*)(Aw + (size_t)ps[tap] * CC + kblk * 8);
        }
        f32x4 acc[2] = {};
#pragma unroll
        for (int tap = 0; tap < 9; ++tap) {
            bf16x8 a = ((vbits >> tap) & 1) ? afw[j % 3][tap] : zero;
#pragma unroll
            for (int nt = 0; nt < 2; ++nt)
                acc[nt] = __builtin_amdgcn_mfma_f32_16x16x32_bf16(a, Bw[tap][nt], acc[nt], 0, 0, 0);
        }
        float mkr[4] = {mks[j].x, mks[j].y, mks[j].z, mks[j].w};
#pragma unroll
        for (int nt = 0; nt < 2; ++nt)
#pragma unroll
            for (int r = 0; r < 4; ++r)
                agg[nt][r] = fmaxf(agg[nt][r], (acc[nt][r] + acce[nt][r]) * mkr[r]);
    }

    // f = agg + skip(egocl bf16) -> per-wave LDS transpose -> mlp MFMA
#pragma unroll
    for (int nt = 0; nt < 2; ++nt)
#pragma unroll
        for (int r = 0; r < 4; ++r) {
            int pixl = kblk * 4 + r;
            float skip = bf2f(egocl[((size_t)b * HWs + p0 + pixl) * CC + nt * 16 + lo]);
            fl[wv * 16 + pixl][nt * 16 + lo] = agg[nt][r] + skip;
        }
    // same-wave LDS read-back (lgkmcnt ordering; no cross-wave sharing)
    bf16x8 Afm;
#pragma unroll
    for (int e = 0; e < 8; ++e)
        Afm[e] = (short)f2bf(fl[wv * 16 + lo][kblk * 8 + e]);

#pragma unroll
    for (int nt2 = 0; nt2 < 2; ++nt2) {
        bf16x8 Bm = ldfrag(wlds, 576 + nt2 * 16 + lo, kblk);
        f32x4 om = {};
        om = __builtin_amdgcn_mfma_f32_16x16x32_bf16(Afm, Bm, om, 0, 0, 0);
        float mb2 = mlp_b[nt2 * 16 + lo];
        int d = nt2 * 16 + lo;
#pragma unroll
        for (int r = 0; r < 4; ++r)
            out[((size_t)b * CC + d) * HWs + p0 + kblk * 4 + r] = om[r] + mb2;
    }
}

extern "C" void kernel_launch(void* const* d_in, const int* in_sizes, int n_in,
                              void* d_out, int out_size, void* d_ws, size_t ws_size,
                              hipStream_t stream)
{
    (void)in_sizes; (void)n_in; (void)out_size; (void)ws_size;
    const float* x     = (const float*)d_in[0];
    // d_in[1] = record_len (unused by reference)
    const float* M     = (const float*)d_in[2];
    const float* msg_w = (const float*)d_in[3];
    const float* msg_b = (const float*)d_in[4];
    const float* mlp_w = (const float*)d_in[5];
    const float* mlp_b = (const float*)d_in[6];
    float* out = (float*)d_out;

    // workspace layout (all segments 16B-aligned; Wp2 contiguous after Wp)
    unsigned short* Wp       = (unsigned short*)d_ws;                    // 18432 bf16
    unsigned short* Wp2      = Wp + 2 * 9 * 32 * 32;                     // 1024 bf16
    unsigned short* warpedcl = Wp2 + 32 * 32;                            // BL*HW*C bf16
    unsigned short* egocl    = warpedcl + (size_t)BL * HWs * CC;         // BB*HW*C bf16
    float*          maskb    = (float*)(egocl + (size_t)BB * HWs * CC);  // BL*HW f32

    {
        k_prep<<<dim3(1716), 256, 0, stream>>>(x, M, msg_w, mlp_w,
                                               warpedcl, egocl, maskb, Wp, Wp2);
    }
    {
        dim3 g(HWs / 64, BB);                // (132, 2)
        k_fused<<<g, 256, 0, stream>>>(warpedcl, egocl, maskb, Wp, Wp2,
                                       msg_b, mlp_b, out);
    }
}